// Round 1
// baseline (2346.435 us; speedup 1.0000x reference)
//
#include <hip/hip_runtime.h>
#include <hip/hip_bf16.h>

// Additive coupling (RealNVP) forward: y = interleave(x1 + MLP(x2), x2)
// MLP: 6 chained GEMMs, fp32 reference. Strategy: split-bf16 (hi+lo) MFMA,
// acc += Ah*Bh + Ah*Bl + Al*Bh in fp32 -> ~1e-4 abs error, 3x bf16 MFMA work.

#define B_DIM    4096
#define D_DIM    2048
#define HALF_DIM 1024
#define MID_DIM  4096
#define NHID     4

typedef __attribute__((ext_vector_type(8))) short frag_ab;   // 8 bf16
typedef __attribute__((ext_vector_type(4))) float frag_cd;   // 4 f32

#define GAS __attribute__((address_space(1)))
#define LAS __attribute__((address_space(3)))

// bf16 round-to-nearest-even from fp32 (bit-level, avoids header type issues)
__device__ __forceinline__ ushort f2bf_rtn(float v) {
    unsigned u = __builtin_bit_cast(unsigned, v);
    unsigned r = u + 0x7FFFu + ((u >> 16) & 1u);
    return (ushort)(r >> 16);
}
__device__ __forceinline__ void split_hilo(float v, ushort& h, ushort& l) {
    h = f2bf_rtn(v);
    float fh = __builtin_bit_cast(float, (unsigned)h << 16);
    l = f2bf_rtn(v - fh);
}

// ---------------------------------------------------------------------------
// prep: x2 = x[:, 2c+1] -> hi/lo bf16; also forward log_det_J scalar.
__global__ __launch_bounds__(256) void prep_x2(const float* __restrict__ x,
                                               const float* __restrict__ logd,
                                               ushort* __restrict__ x2h,
                                               ushort* __restrict__ x2l,
                                               float* __restrict__ outLog) {
    int idx = blockIdx.x * 256 + threadIdx.x;        // 0 .. B*HALF-1
    if (idx == 0) outLog[0] = logd[0];
    float2 v = ((const float2*)x)[idx];              // (x[b][2c], x[b][2c+1])
    ushort h, l;
    split_hilo(v.y, h, l);                           // MASK=1: x2 = odd lanes
    x2h[idx] = h; x2l[idx] = l;
}

// ---------------------------------------------------------------------------
// transpose + split: in (K x N) f32 row-major -> out (N x K) bf16 hi/lo.
__global__ __launch_bounds__(256) void transpose_split(const float* __restrict__ in,
                                                       int K, int N,
                                                       ushort* __restrict__ outH,
                                                       ushort* __restrict__ outL) {
    __shared__ float tile[64][65];                   // +1 pad: conflict-free
    const int n0 = blockIdx.x * 64, k0 = blockIdx.y * 64;
    const int t = threadIdx.x;
    const int c = t & 63, g = t >> 6;                // g = 0..3
#pragma unroll
    for (int r = 0; r < 16; ++r) {
        int row = g * 16 + r;
        tile[row][c] = in[(size_t)(k0 + row) * N + n0 + c];   // coalesced read
    }
    __syncthreads();
#pragma unroll
    for (int r = 0; r < 16; ++r) {
        int nrow = g * 16 + r;
        float v = tile[c][nrow];                     // transposed, pad avoids conflicts
        ushort h, l; split_hilo(v, h, l);
        size_t o = (size_t)(n0 + nrow) * K + k0 + c; // coalesced write
        outH[o] = h; outL[o] = l;
    }
}

// ---------------------------------------------------------------------------
// GEMM: C(M,N) = A(M,K) @ B^T(N,K)^T with A,B in hi/lo bf16 pairs.
// acc accumulates Ah*Bh + Ah*Bl + Al*Bh per K-step via mfma_f32_16x16x32_bf16.
// EPI=0: C = relu(acc+bias) -> hi/lo bf16 (next layer's A)
// EPI=1: y[row][2c] = x[row][2c] + acc+bias; y[row][2c+1] = x[row][2c+1]
template <int EPI>
__global__ __launch_bounds__(256, 2) void gemm_hilo(
    const ushort* __restrict__ Ah, const ushort* __restrict__ Al,
    const ushort* __restrict__ Bh, const ushort* __restrict__ Bl,
    const float* __restrict__ bias,
    int M, int N, int K,
    ushort* __restrict__ Ch, ushort* __restrict__ Cl,
    const float* __restrict__ xin, float* __restrict__ yout) {
    // 128x128 tile, BK=32, 4 waves in 2x2, each wave 64x64 (4x4 frags 16x16)
    __shared__ ushort sAh[4096], sAl[4096], sBh[4096], sBl[4096];  // 8 KB each
    const int t = threadIdx.x;
    const int w = t >> 6, l = t & 63;
    const int m0 = blockIdx.y * 128, n0 = blockIdx.x * 128;
    const int wr = (w >> 1) * 64, wc = (w & 1) * 64;
    const int lr = l & 15, lk = (l >> 4) * 8;

    frag_cd acc[4][4];
#pragma unroll
    for (int i = 0; i < 4; ++i)
#pragma unroll
        for (int j = 0; j < 4; ++j) acc[i][j] = (frag_cd){0.f, 0.f, 0.f, 0.f};

    float bv[4];
#pragma unroll
    for (int j = 0; j < 4; ++j) bv[j] = bias[n0 + wc + j * 16 + lr];

    // staging: thread t loads 16B = 8 bf16; row = t>>2 (64 rows/call), chunk = t&3
    const int srow = t >> 2;
    const int scol = (t & 3) * 8;
    const size_t aBase = (size_t)(m0 + srow) * K + scol;
    const size_t bBase = (size_t)(n0 + srow) * K + scol;
    const size_t rstep = (size_t)64 * K;
    const int lo = w * 512;   // wave-uniform LDS elem offset; HW adds lane*16B

    for (int k0 = 0; k0 < K; k0 += 32) {
        __syncthreads();   // prior compute done before overwrite
        __builtin_amdgcn_global_load_lds((const GAS void*)(Ah + aBase + k0),         (LAS void*)(sAh + lo),        16, 0, 0);
        __builtin_amdgcn_global_load_lds((const GAS void*)(Ah + aBase + rstep + k0), (LAS void*)(sAh + 2048 + lo), 16, 0, 0);
        __builtin_amdgcn_global_load_lds((const GAS void*)(Al + aBase + k0),         (LAS void*)(sAl + lo),        16, 0, 0);
        __builtin_amdgcn_global_load_lds((const GAS void*)(Al + aBase + rstep + k0), (LAS void*)(sAl + 2048 + lo), 16, 0, 0);
        __builtin_amdgcn_global_load_lds((const GAS void*)(Bh + bBase + k0),         (LAS void*)(sBh + lo),        16, 0, 0);
        __builtin_amdgcn_global_load_lds((const GAS void*)(Bh + bBase + rstep + k0), (LAS void*)(sBh + 2048 + lo), 16, 0, 0);
        __builtin_amdgcn_global_load_lds((const GAS void*)(Bl + bBase + k0),         (LAS void*)(sBl + lo),        16, 0, 0);
        __builtin_amdgcn_global_load_lds((const GAS void*)(Bl + bBase + rstep + k0), (LAS void*)(sBl + 2048 + lo), 16, 0, 0);
        __syncthreads();   // compiler drains vmcnt(0) before s_barrier

        frag_ab fah[4], fal[4], fbh[4], fbl[4];
#pragma unroll
        for (int i = 0; i < 4; ++i) {
            fah[i] = *(const frag_ab*)&sAh[(wr + i * 16 + lr) * 32 + lk];
            fal[i] = *(const frag_ab*)&sAl[(wr + i * 16 + lr) * 32 + lk];
            fbh[i] = *(const frag_ab*)&sBh[(wc + i * 16 + lr) * 32 + lk];
            fbl[i] = *(const frag_ab*)&sBl[(wc + i * 16 + lr) * 32 + lk];
        }
#pragma unroll
        for (int i = 0; i < 4; ++i)
#pragma unroll
            for (int j = 0; j < 4; ++j) {
                acc[i][j] = __builtin_amdgcn_mfma_f32_16x16x32_bf16(fah[i], fbh[j], acc[i][j], 0, 0, 0);
                acc[i][j] = __builtin_amdgcn_mfma_f32_16x16x32_bf16(fah[i], fbl[j], acc[i][j], 0, 0, 0);
                acc[i][j] = __builtin_amdgcn_mfma_f32_16x16x32_bf16(fal[i], fbh[j], acc[i][j], 0, 0, 0);
            }
    }

    // epilogue: C/D layout col = lane&15, row = (lane>>4)*4 + reg
#pragma unroll
    for (int i = 0; i < 4; ++i) {
        const int rowb = m0 + wr + i * 16 + (l >> 4) * 4;
#pragma unroll
        for (int j = 0; j < 4; ++j) {
            const int col = n0 + wc + j * 16 + lr;
#pragma unroll
            for (int r = 0; r < 4; ++r) {
                float v = acc[i][j][r] + bv[j];
                const int row = rowb + r;
                if (EPI == 0) {
                    v = fmaxf(v, 0.0f);
                    ushort h, lo16; split_hilo(v, h, lo16);
                    size_t o = (size_t)row * N + col;
                    Ch[o] = h; Cl[o] = lo16;
                } else {
                    const float2 xv = *(const float2*)(xin + (size_t)row * D_DIM + 2 * col);
                    float2 yv; yv.x = xv.x + v; yv.y = xv.y;
                    *(float2*)(yout + (size_t)row * D_DIM + 2 * col) = yv;
                }
            }
        }
    }
}

// ---------------------------------------------------------------------------
extern "C" void kernel_launch(void* const* d_in, const int* in_sizes, int n_in,
                              void* d_out, int out_size, void* d_ws, size_t ws_size,
                              hipStream_t stream) {
    const float* x     = (const float*)d_in[0];
    const float* logd  = (const float*)d_in[1];
    const float* W_in  = (const float*)d_in[2];
    const float* b_in  = (const float*)d_in[3];
    const float* W_h   = (const float*)d_in[4];
    const float* b_h   = (const float*)d_in[5];
    const float* W_out = (const float*)d_in[6];
    const float* b_out = (const float*)d_in[7];
    float* y = (float*)d_out;

    // workspace layout (208 MB total)
    char* ws = (char*)d_ws;
    ushort* x2h = (ushort*)(ws);                      //  8 MB (4096x1024 bf16)
    ushort* x2l = (ushort*)(ws + (size_t)8  * (1 << 20));
    ushort* wth = (ushort*)(ws + (size_t)16 * (1 << 20));  // 32 MB (<=4096x4096)
    ushort* wtl = (ushort*)(ws + (size_t)48 * (1 << 20));
    ushort* h0h = (ushort*)(ws + (size_t)80 * (1 << 20));  // 32 MB each
    ushort* h0l = (ushort*)(ws + (size_t)112 * (1 << 20));
    ushort* h1h = (ushort*)(ws + (size_t)144 * (1 << 20));
    ushort* h1l = (ushort*)(ws + (size_t)176 * (1 << 20));

    prep_x2<<<dim3(B_DIM * HALF_DIM / 256), 256, 0, stream>>>(
        x, logd, x2h, x2l, y + (size_t)B_DIM * D_DIM);

    // L0: h0 = relu(x2 @ W_in + b_in)       (K=1024, N=4096)
    transpose_split<<<dim3(MID_DIM / 64, HALF_DIM / 64), 256, 0, stream>>>(
        W_in, HALF_DIM, MID_DIM, wth, wtl);
    gemm_hilo<0><<<dim3(MID_DIM / 128, B_DIM / 128), 256, 0, stream>>>(
        x2h, x2l, wth, wtl, b_in, B_DIM, MID_DIM, HALF_DIM, h0h, h0l, nullptr, nullptr);

    // L1..L4: h = relu(h @ W_h[i] + b_h[i]) (4096^3)
    ushort *ah = h0h, *al = h0l, *ch = h1h, *cl = h1l;
    for (int i = 0; i < NHID; ++i) {
        transpose_split<<<dim3(MID_DIM / 64, MID_DIM / 64), 256, 0, stream>>>(
            W_h + (size_t)i * MID_DIM * MID_DIM, MID_DIM, MID_DIM, wth, wtl);
        gemm_hilo<0><<<dim3(MID_DIM / 128, B_DIM / 128), 256, 0, stream>>>(
            ah, al, wth, wtl, b_h + (size_t)i * MID_DIM, B_DIM, MID_DIM, MID_DIM,
            ch, cl, nullptr, nullptr);
        ushort* th = ah; ah = ch; ch = th;
        ushort* tl = al; al = cl; cl = tl;
    }

    // L5: y_even = x_even + (h @ W_out + b_out); y_odd = x_odd  (K=4096, N=1024)
    transpose_split<<<dim3(HALF_DIM / 64, MID_DIM / 64), 256, 0, stream>>>(
        W_out, MID_DIM, HALF_DIM, wth, wtl);
    gemm_hilo<1><<<dim3(HALF_DIM / 128, B_DIM / 128), 256, 0, stream>>>(
        ah, al, wth, wtl, b_out, B_DIM, HALF_DIM, MID_DIM, nullptr, nullptr, x, y);

    (void)in_sizes; (void)n_in; (void)out_size; (void)ws_size;
}

// Round 3
// 1891.239 us; speedup vs baseline: 1.2407x; 1.2407x over previous
//
#include <hip/hip_runtime.h>
#include <hip/hip_bf16.h>

// Additive coupling forward via split-bf16 MFMA (Ah*Bh + Ah*Bl + Al*Bh).
// Round 2 (resubmit): 256^2 tile, 8-wave, BK=32, double-buffered LDS with
// next-tile prefetch issued right after the barrier (hides the vmcnt drain),
// and a packed-swizzled operand format making ds_read_b128 conflict-free.
//
// Packed format for matrix X (R x K):  Xp[((r*K/32 + kt))*64 + pos*8 + e]
//   element (r,k): kt=k>>5, chunk c=(k&31)>>3 (hi) or 4+((k&31)>>3) (lo),
//   e=k&7, stored chunk position pos = c ^ (r&7).
// Row-tile image = exactly the (swizzled) LDS image -> global_load_lds
// copies 128B rows linearly; reads XOR with row&7. Bank start =
// ((c^(r&7))*4)%32, row stride 128B = full bank wrap -> conflict-free.

#define B_DIM    4096
#define D_DIM    2048
#define HALF_DIM 1024
#define MID_DIM  4096
#define NHID     4

typedef __attribute__((ext_vector_type(8))) short frag_ab;   // 8 bf16
typedef __attribute__((ext_vector_type(4))) float frag_cd;   // 4 f32

#define GAS __attribute__((address_space(1)))
#define LAS __attribute__((address_space(3)))

__device__ __forceinline__ ushort f2bf_rtn(float v) {
    unsigned u = __builtin_bit_cast(unsigned, v);
    unsigned r = u + 0x7FFFu + ((u >> 16) & 1u);
    return (ushort)(r >> 16);
}
__device__ __forceinline__ void split_hilo(float v, ushort& h, ushort& l) {
    h = f2bf_rtn(v);
    float fh = __builtin_bit_cast(float, (unsigned)h << 16);
    l = f2bf_rtn(v - fh);
}

// ---------------------------------------------------------------------------
// prep: x2 = x[:, 2c+1] -> packed-swizzled bf16 hi/lo; forward log_det_J.
__global__ __launch_bounds__(256) void prep_x2(const float* __restrict__ x,
                                               const float* __restrict__ logd,
                                               ushort* __restrict__ x2p,
                                               float* __restrict__ outLog) {
    int idx = blockIdx.x * 256 + threadIdx.x;        // 0 .. B*HALF-1
    if (idx == 0) outLog[0] = logd[0];
    int b = idx >> 10, c = idx & 1023;
    float2 v = ((const float2*)x)[idx];              // (x[b][2c], x[b][2c+1])
    ushort h, l; split_hilo(v.y, h, l);
    int kt = c >> 5, w = c & 31;
    int pos = (w >> 3) ^ (b & 7);
    size_t base = ((size_t)(b * 32 + kt)) * 64 + (w & 7);   // PK = 1024/32 = 32
    x2p[base + pos * 8]       = h;
    x2p[base + (pos ^ 4) * 8] = l;
}

// ---------------------------------------------------------------------------
// transpose + split: in (K x N) f32 row-major -> packed-swizzled (N rows, K).
__global__ __launch_bounds__(256) void transpose_split(const float* __restrict__ in,
                                                       int K, int N,
                                                       ushort* __restrict__ outP) {
    __shared__ float tile[64][65];
    const int n0 = blockIdx.x * 64, k0 = blockIdx.y * 64;
    const int t = threadIdx.x;
    const int c = t & 63, g = t >> 6;
#pragma unroll
    for (int r = 0; r < 16; ++r)
        tile[g * 16 + r][c] = in[(size_t)(k0 + g * 16 + r) * N + n0 + c];
    __syncthreads();
    const int PK = K >> 5;
#pragma unroll
    for (int r = 0; r < 16; ++r) {
        int nrow = g * 16 + r;
        float v = tile[c][nrow];                     // = in[k0+c][n0+nrow]
        int n = n0 + nrow, k = k0 + c;
        ushort h, l; split_hilo(v, h, l);
        int kt = k >> 5, w = k & 31;
        int pos = (w >> 3) ^ (n & 7);
        size_t base = ((size_t)n * PK + kt) * 64 + (w & 7);
        outP[base + pos * 8]       = h;
        outP[base + (pos ^ 4) * 8] = l;
    }
}

// ---------------------------------------------------------------------------
// gemm8: 256x256 tile, 8 waves (2Mx4N), BK=32, dbuf + next-tile prefetch.
// C = relu(A@B^T + bias) -> packed-swizzled output (next layer's A).
// A: M=4096 rows packed (PK=K/32); B: N=4096 rows packed; grid = 256 blocks.
__global__ __launch_bounds__(512, 2) void gemm8(
    const ushort* __restrict__ Ap, const ushort* __restrict__ Bp,
    const float* __restrict__ bias, int K, int N,
    ushort* __restrict__ Cp) {
    __shared__ ushort sA[2][16384];                  // 2 x 256 x 64  (64 KB)
    __shared__ ushort sB[2][16384];                  // 64 KB
    const int t = threadIdx.x;
    const int w = t >> 6, l = t & 63;
    const int bid = blockIdx.x;
    const int swz = (bid & 7) * 32 + (bid >> 3);     // bijective (256 % 8 == 0)
    const int bx = swz & 15, by = swz >> 4;          // N/256 = 16
    const int m0 = by * 256, n0 = bx * 256;
    const int wr = w >> 2, wc = w & 3;               // wave 128x64 output
    const int lr = l & 15, lc = l >> 4;              // lc = 0..3
    const int PK = K >> 5, NK = PK;

    // staging: thread t -> row t>>3 (of 64/call), chunk t&7 (16B)
    const ushort* aSrc = Ap + (size_t)(m0 + (t >> 3)) * (PK * 64) + (t & 7) * 8;
    const ushort* bSrc = Bp + (size_t)(n0 + (t >> 3)) * (PK * 64) + (t & 7) * 8;
    const size_t qstep = (size_t)64 * PK * 64;       // 64 rows
    const int ldsBase = w * 512;                     // + q*4096; HW adds lane*16B

#define STAGE8(buf, kt) do {                                                         \
    const ushort* _as = aSrc + (size_t)(kt) * 64;                                    \
    const ushort* _bs = bSrc + (size_t)(kt) * 64;                                    \
    _Pragma("unroll")                                                                \
    for (int q = 0; q < 4; ++q) {                                                    \
        __builtin_amdgcn_global_load_lds((const GAS void*)(_as + q * qstep),         \
                                         (LAS void*)&sA[buf][q * 4096 + ldsBase], 16, 0, 0); \
        __builtin_amdgcn_global_load_lds((const GAS void*)(_bs + q * qstep),         \
                                         (LAS void*)&sB[buf][q * 4096 + ldsBase], 16, 0, 0); \
    } } while (0)

    frag_cd acc[8][4];
#pragma unroll
    for (int i = 0; i < 8; ++i)
#pragma unroll
        for (int j = 0; j < 4; ++j) acc[i][j] = (frag_cd){0.f, 0.f, 0.f, 0.f};

    float bv[4];
#pragma unroll
    for (int j = 0; j < 4; ++j) bv[j] = bias[n0 + wc * 64 + j * 16 + lr];

    STAGE8(0, 0);
    for (int kt = 0; kt < NK; ++kt) {
        const int cur = kt & 1;
        __syncthreads();                 // drains own vmcnt -> buf[cur] staged by all
        if (kt + 1 < NK) STAGE8(cur ^ 1, kt + 1);   // prefetch: full tile of compute to land

        frag_ab fbh[4], fbl[4];
#pragma unroll
        for (int j = 0; j < 4; ++j) {
            int row = wc * 64 + j * 16 + lr;
            int ph = lc ^ (row & 7);
            fbh[j] = *(const frag_ab*)&sB[cur][row * 64 + ph * 8];
            fbl[j] = *(const frag_ab*)&sB[cur][row * 64 + (ph ^ 4) * 8];
        }
#pragma unroll
        for (int mh = 0; mh < 2; ++mh) {
            frag_ab fah[4], fal[4];
#pragma unroll
            for (int i = 0; i < 4; ++i) {
                int row = wr * 128 + mh * 64 + i * 16 + lr;
                int ph = lc ^ (row & 7);
                fah[i] = *(const frag_ab*)&sA[cur][row * 64 + ph * 8];
                fal[i] = *(const frag_ab*)&sA[cur][row * 64 + (ph ^ 4) * 8];
            }
            __builtin_amdgcn_s_setprio(1);
#pragma unroll
            for (int i = 0; i < 4; ++i)
#pragma unroll
                for (int j = 0; j < 4; ++j) {
                    acc[mh * 4 + i][j] = __builtin_amdgcn_mfma_f32_16x16x32_bf16(fah[i], fbh[j], acc[mh * 4 + i][j], 0, 0, 0);
                    acc[mh * 4 + i][j] = __builtin_amdgcn_mfma_f32_16x16x32_bf16(fah[i], fbl[j], acc[mh * 4 + i][j], 0, 0, 0);
                    acc[mh * 4 + i][j] = __builtin_amdgcn_mfma_f32_16x16x32_bf16(fal[i], fbh[j], acc[mh * 4 + i][j], 0, 0, 0);
                }
            __builtin_amdgcn_s_setprio(0);
        }
    }
#undef STAGE8

    // epilogue: C/D col = lane&15, row = (lane>>4)*4 + reg
    const int PKo = N >> 5;
#pragma unroll
    for (int i = 0; i < 8; ++i) {
#pragma unroll
        for (int j = 0; j < 4; ++j) {
            const int col = n0 + wc * 64 + j * 16 + lr;
            const int kto = col >> 5, w32 = col & 31;
            const int e = w32 & 7, ch = w32 >> 3;
#pragma unroll
            for (int r = 0; r < 4; ++r) {
                const int row = m0 + wr * 128 + i * 16 + lc * 4 + r;
                float v = fmaxf(acc[i][j][r] + bv[j], 0.0f);
                ushort h, lo16; split_hilo(v, h, lo16);
                const int pos = ch ^ (row & 7);
                size_t basec = ((size_t)row * PKo + kto) * 64 + e;
                Cp[basec + pos * 8]       = h;
                Cp[basec + (pos ^ 4) * 8] = lo16;
            }
        }
    }
}

// ---------------------------------------------------------------------------
// gemm2: 128x128 tile, 4 waves, same pipeline; epilogue fuses x-add + interleave.
// Used for L5 (N=1024): grid (M/128)*(N/128) = 256 blocks.
__global__ __launch_bounds__(256, 2) void gemm2(
    const ushort* __restrict__ Ap, const ushort* __restrict__ Bp,
    const float* __restrict__ bias, int K, int N,
    const float* __restrict__ xin, float* __restrict__ yout) {
    __shared__ ushort sA[2][8192];                   // 2 x 128 x 64 (32 KB)
    __shared__ ushort sB[2][8192];
    const int t = threadIdx.x;
    const int w = t >> 6, l = t & 63;
    const int bid = blockIdx.x;
    const int swz = (bid & 7) * 32 + (bid >> 3);
    const int bx = swz & 7, by = swz >> 3;           // N/128 = 8, M/128 = 32
    const int m0 = by * 128, n0 = bx * 128;
    const int wr = w >> 1, wc = w & 1;               // wave 64x64 output
    const int lr = l & 15, lc = l >> 4;
    const int PK = K >> 5, NK = PK;

    const ushort* aSrc = Ap + (size_t)(m0 + (t >> 3)) * (PK * 64) + (t & 7) * 8;
    const ushort* bSrc = Bp + (size_t)(n0 + (t >> 3)) * (PK * 64) + (t & 7) * 8;
    const size_t qstep = (size_t)32 * PK * 64;       // 32 rows / call
    const int ldsBase = w * 512;                     // + q*2048

#define STAGE2(buf, kt) do {                                                         \
    const ushort* _as = aSrc + (size_t)(kt) * 64;                                    \
    const ushort* _bs = bSrc + (size_t)(kt) * 64;                                    \
    _Pragma("unroll")                                                                \
    for (int q = 0; q < 4; ++q) {                                                    \
        __builtin_amdgcn_global_load_lds((const GAS void*)(_as + q * qstep),         \
                                         (LAS void*)&sA[buf][q * 2048 + ldsBase], 16, 0, 0); \
        __builtin_amdgcn_global_load_lds((const GAS void*)(_bs + q * qstep),         \
                                         (LAS void*)&sB[buf][q * 2048 + ldsBase], 16, 0, 0); \
    } } while (0)

    frag_cd acc[4][4];
#pragma unroll
    for (int i = 0; i < 4; ++i)
#pragma unroll
        for (int j = 0; j < 4; ++j) acc[i][j] = (frag_cd){0.f, 0.f, 0.f, 0.f};

    float bv[4];
#pragma unroll
    for (int j = 0; j < 4; ++j) bv[j] = bias[n0 + wc * 64 + j * 16 + lr];

    STAGE2(0, 0);
    for (int kt = 0; kt < NK; ++kt) {
        const int cur = kt & 1;
        __syncthreads();
        if (kt + 1 < NK) STAGE2(cur ^ 1, kt + 1);

        frag_ab fah[4], fal[4], fbh[4], fbl[4];
#pragma unroll
        for (int i = 0; i < 4; ++i) {
            int rowa = wr * 64 + i * 16 + lr;
            int pa = lc ^ (rowa & 7);
            fah[i] = *(const frag_ab*)&sA[cur][rowa * 64 + pa * 8];
            fal[i] = *(const frag_ab*)&sA[cur][rowa * 64 + (pa ^ 4) * 8];
            int rowb = wc * 64 + i * 16 + lr;
            int pb = lc ^ (rowb & 7);
            fbh[i] = *(const frag_ab*)&sB[cur][rowb * 64 + pb * 8];
            fbl[i] = *(const frag_ab*)&sB[cur][rowb * 64 + (pb ^ 4) * 8];
        }
        __builtin_amdgcn_s_setprio(1);
#pragma unroll
        for (int i = 0; i < 4; ++i)
#pragma unroll
            for (int j = 0; j < 4; ++j) {
                acc[i][j] = __builtin_amdgcn_mfma_f32_16x16x32_bf16(fah[i], fbh[j], acc[i][j], 0, 0, 0);
                acc[i][j] = __builtin_amdgcn_mfma_f32_16x16x32_bf16(fah[i], fbl[j], acc[i][j], 0, 0, 0);
                acc[i][j] = __builtin_amdgcn_mfma_f32_16x16x32_bf16(fal[i], fbh[j], acc[i][j], 0, 0, 0);
            }
        __builtin_amdgcn_s_setprio(0);
    }
#undef STAGE2

    // epilogue: y[row][2c] = x[row][2c] + (acc+bias); y[row][2c+1] = x[row][2c+1]
#pragma unroll
    for (int i = 0; i < 4; ++i) {
#pragma unroll
        for (int j = 0; j < 4; ++j) {
            const int col = n0 + wc * 64 + j * 16 + lr;
#pragma unroll
            for (int r = 0; r < 4; ++r) {
                const int row = m0 + wr * 64 + i * 16 + lc * 4 + r;
                float v = acc[i][j][r] + bv[j];
                const float2 xv = ((const float2*)xin)[(size_t)row * (D_DIM / 2) + col];
                float2 yv; yv.x = xv.x + v; yv.y = xv.y;
                ((float2*)yout)[(size_t)row * (D_DIM / 2) + col] = yv;
            }
        }
    }
}

// ---------------------------------------------------------------------------
extern "C" void kernel_launch(void* const* d_in, const int* in_sizes, int n_in,
                              void* d_out, int out_size, void* d_ws, size_t ws_size,
                              hipStream_t stream) {
    const float* x     = (const float*)d_in[0];
    const float* logd  = (const float*)d_in[1];
    const float* W_in  = (const float*)d_in[2];
    const float* b_in  = (const float*)d_in[3];
    const float* W_h   = (const float*)d_in[4];
    const float* b_h   = (const float*)d_in[5];
    const float* W_out = (const float*)d_in[6];
    const float* b_out = (const float*)d_in[7];
    float* y = (float*)d_out;

    // workspace layout (208 MB): x2p 16MB | Wp 64MB | h0 64MB | h1 64MB
    char* ws = (char*)d_ws;
    ushort* x2p = (ushort*)(ws);
    ushort* wp  = (ushort*)(ws + (size_t)16  * (1 << 20));
    ushort* h0  = (ushort*)(ws + (size_t)80  * (1 << 20));
    ushort* h1  = (ushort*)(ws + (size_t)144 * (1 << 20));

    prep_x2<<<dim3(B_DIM * HALF_DIM / 256), 256, 0, stream>>>(
        x, logd, x2p, y + (size_t)B_DIM * D_DIM);

    // L0: h0 = relu(x2 @ W_in + b_in)   (K=1024, N=4096)
    transpose_split<<<dim3(MID_DIM / 64, HALF_DIM / 64), 256, 0, stream>>>(
        W_in, HALF_DIM, MID_DIM, wp);
    gemm8<<<dim3(256), 512, 0, stream>>>(x2p, wp, b_in, HALF_DIM, MID_DIM, h0);

    // L1..L4: h = relu(h @ W_h[i] + b_h[i])  (4096^3)
    ushort *ah = h0, *ch = h1;
    for (int i = 0; i < NHID; ++i) {
        transpose_split<<<dim3(MID_DIM / 64, MID_DIM / 64), 256, 0, stream>>>(
            W_h + (size_t)i * MID_DIM * MID_DIM, MID_DIM, MID_DIM, wp);
        gemm8<<<dim3(256), 512, 0, stream>>>(ah, wp, b_h + (size_t)i * MID_DIM,
                                             MID_DIM, MID_DIM, ch);
        ushort* tmp = ah; ah = ch; ch = tmp;
    }

    // L5: y_even = x_even + (h @ W_out + b_out); y_odd = x_odd  (K=4096, N=1024)
    transpose_split<<<dim3(HALF_DIM / 64, MID_DIM / 64), 256, 0, stream>>>(
        W_out, MID_DIM, HALF_DIM, wp);
    gemm2<<<dim3(256), 256, 0, stream>>>(ah, wp, b_out, MID_DIM, HALF_DIM, x, y);

    (void)in_sizes; (void)n_in; (void)out_size; (void)ws_size;
}